// Round 4
// baseline (231.892 us; speedup 1.0000x reference)
//
#include <hip/hip_runtime.h>

#define C_CH 128
#define N_EL 262144          // 512*512 per channel
#define NBINS 256
#define FB 4096              // fine bins used: 0..4080 (4080 = 16*255)
#define FBINS 4080.0f
#define BPC_MM 16            // blocks per channel, minmax pass
#define BPC_H 4              // blocks per channel, hist pass
typedef unsigned long long u64;

// padded LDS index: +1 float per 32 to break 32-way bank conflicts on tid*16 slices
#define PIDX(i) ((i) + ((i) >> 5))
#define FBP (FB + (FB >> 5))

// ---------------- pass A: per-block min/max/sumx2 partials (plain stores, no init needed)
__global__ __launch_bounds__(256) void k_minmax(const float* __restrict__ inp,
                                                const float* __restrict__ mask,
                                                float* __restrict__ pmn,
                                                float* __restrict__ pmx,
                                                float* __restrict__ sx2p) {
  const int SEG = N_EL / BPC_MM;      // 16384 elements, 4096 float4
  int c = blockIdx.x / BPC_MM;
  int seg = blockIdx.x % BPC_MM;
  const float4* in4 = (const float4*)(inp + (size_t)c * N_EL + (size_t)seg * SEG);
  const float4* mk4 = (const float4*)(mask + (size_t)seg * SEG);
  float mn = INFINITY, mx = -INFINITY, sx2 = 0.f;
  int tid = threadIdx.x;
#pragma unroll
  for (int i = 0; i < 4; ++i) {
    float4 av[4], mv[4];
#pragma unroll
    for (int k = 0; k < 4; ++k) av[k] = in4[i * 1024 + k * 256 + tid];
#pragma unroll
    for (int k = 0; k < 4; ++k) mv[k] = mk4[i * 1024 + k * 256 + tid];
#pragma unroll
    for (int k = 0; k < 4; ++k) {
      float x0 = av[k].x * mv[k].x, x1 = av[k].y * mv[k].y;
      float x2 = av[k].z * mv[k].z, x3 = av[k].w * mv[k].w;
      mn = fminf(mn, fminf(fminf(x0, x1), fminf(x2, x3)));
      mx = fmaxf(mx, fmaxf(fmaxf(x0, x1), fmaxf(x2, x3)));
      sx2 += x0 * x0 + x1 * x1 + x2 * x2 + x3 * x3;
    }
  }
  for (int o = 32; o > 0; o >>= 1) {
    mn = fminf(mn, __shfl_xor(mn, o));
    mx = fmaxf(mx, __shfl_xor(mx, o));
    sx2 += __shfl_xor(sx2, o);
  }
  __shared__ float smn[4], smx[4], ssx[4];
  if ((tid & 63) == 0) { smn[tid >> 6] = mn; smx[tid >> 6] = mx; ssx[tid >> 6] = sx2; }
  __syncthreads();
  if (tid == 0) {
    pmn[blockIdx.x] = fminf(fminf(smn[0], smn[1]), fminf(smn[2], smn[3]));
    pmx[blockIdx.x] = fmaxf(fmaxf(smx[0], smx[1]), fmaxf(smx[2], smx[3]));
    sx2p[blockIdx.x] = ssx[0] + ssx[1] + ssx[2] + ssx[3];
  }
}

// ---------------- pass B: LDS fine hist (packed u64), plain-store flush to disjoint slices
__global__ __launch_bounds__(1024) void k_hist(const float* __restrict__ inp,
                                               const float* __restrict__ mask,
                                               const float* __restrict__ pmn,
                                               const float* __restrict__ pmx,
                                               u64* __restrict__ fineP,
                                               float* __restrict__ dout) {
  __shared__ u64 lh[FB];              // 32 KB: (cnt<<46) | sum(frac * 2^28)
  __shared__ float sMnMx[2];
  const int SEG = N_EL / BPC_H;       // 65536 elements, 16384 float4
  int c = blockIdx.x / BPC_H, seg = blockIdx.x % BPC_H;
  int tid = threadIdx.x;
  for (int i = tid; i < FB; i += 1024) lh[i] = 0ull;
  if (tid == 0) {
    float m = INFINITY;
    for (int k = 0; k < BPC_MM; ++k) m = fminf(m, pmn[c * BPC_MM + k]);
    sMnMx[0] = m;
    if (blockIdx.x == 0) dout[0] = 0.f;   // loss accumulator for k_fin
  }
  if (tid == 64) {
    float M = -INFINITY;
    for (int k = 0; k < BPC_MM; ++k) M = fmaxf(M, pmx[c * BPC_MM + k]);
    sMnMx[1] = M;
  }
  __syncthreads();
  float mn = sMnMx[0], mx = sMnMx[1];
  float inv = FBINS / fmaxf(mx - mn, 1e-8f);
  const float4* in4 = (const float4*)(inp + (size_t)c * N_EL + (size_t)seg * SEG);
  const float4* mk4 = (const float4*)(mask + (size_t)seg * SEG);
#pragma unroll
  for (int i = 0; i < 4; ++i) {
    float4 av[4], mv[4];
#pragma unroll
    for (int k = 0; k < 4; ++k) av[k] = in4[i * 4096 + k * 1024 + tid];
#pragma unroll
    for (int k = 0; k < 4; ++k) mv[k] = mk4[i * 4096 + k * 1024 + tid];
#pragma unroll
    for (int k = 0; k < 4; ++k) {
      float xs[4] = {av[k].x * mv[k].x, av[k].y * mv[k].y, av[k].z * mv[k].z, av[k].w * mv[k].w};
#pragma unroll
      for (int e = 0; e < 4; ++e) {
        float vv = (xs[e] - mn) * inv;             // position in fine-bin units
        vv = fminf(fmaxf(vv, 0.f), FBINS);         // [0, 4080]
        int fb = (int)vv;
        float frac = vv - (float)fb;               // [0,1)
        u64 pkt = (1ull << 46) | (u64)(frac * 268435456.0f);  // frac * 2^28
        atomicAdd(&lh[fb], pkt);
      }
    }
  }
  __syncthreads();   // order all LDS atomics before flush
  // flush fine hist: plain u64 stores, disjoint per-block slice
  for (int i = tid; i < FB; i += 1024) fineP[(size_t)blockIdx.x * FB + i] = lh[i];
}

// inclusive block scan of (a,b) over 256 threads: wave shfl scan + wave-total combine
__device__ __forceinline__ void blockScan2(float& a, float& b, float* tA, float* tB, int tid) {
  int lane = tid & 63, wave = tid >> 6;
#pragma unroll
  for (int o = 1; o < 64; o <<= 1) {
    float na = __shfl_up(a, o), nb = __shfl_up(b, o);
    if (lane >= o) { a += na; b += nb; }
  }
  if (lane == 63) { tA[wave] = a; tB[wave] = b; }
  __syncthreads();
  float offA = 0.f, offB = 0.f;
  for (int wv = 0; wv < 3; ++wv)
    if (wv < wave) { offA += tA[wv]; offB += tB[wv]; }
  a += offA; b += offB;
  __syncthreads();
}

// ---------------- pass C: scans + searchsorted-equivalent + loss
__global__ __launch_bounds__(256) void k_fin(const float* __restrict__ th,
                                             const float* __restrict__ tmn_p,
                                             const float* __restrict__ tmx_p,
                                             const float* __restrict__ pmn,
                                             const float* __restrict__ pmx,
                                             const float* __restrict__ sx2p,
                                             const u64* __restrict__ fineP,
                                             float* __restrict__ dout) {
  __shared__ float sCnt[FBP], sPos[FBP];
  __shared__ float tA[4], tB[4];
  __shared__ float sCdf[NBINS];
  __shared__ float sS1[NBINS];
  __shared__ int sK[NBINS];
  __shared__ float red[4];
  __shared__ float sMnMx[2];
  int c = blockIdx.x, tid = threadIdx.x;
  if (tid == 0) {
    float m = INFINITY;
    for (int k = 0; k < BPC_MM; ++k) m = fminf(m, pmn[c * BPC_MM + k]);
    sMnMx[0] = m;
  }
  if (tid == 64) {
    float M = -INFINITY;
    for (int k = 0; k < BPC_MM; ++k) M = fmaxf(M, pmx[c * BPC_MM + k]);
    sMnMx[1] = M;
  }
  const u64 FMASK = (1ull << 46) - 1;
  for (int i = tid; i < FB; i += 256) {
    u64 csum = 0ull, fsum = 0ull;
#pragma unroll
    for (int p = 0; p < BPC_H; ++p) {
      u64 pk = fineP[(size_t)(c * BPC_H + p) * FB + i];
      csum += pk >> 46;
      fsum += pk & FMASK;
    }
    float cn = (float)(unsigned)csum;
    sCnt[PIDX(i)] = cn;
    sPos[PIDX(i)] = cn * (float)i + (float)fsum * (1.0f / 268435456.0f);
  }
  __syncthreads();
  float mn = sMnMx[0], mx = sMnMx[1];
  float w = fmaxf(mx - mn, 1e-8f) / FBINS;        // fine-bin width
  // inclusive scan: 16-elem serial per thread, then parallel scan of thread totals
  float a = 0.f, b = 0.f;
  {
    int base = tid * (FB / 256);
    for (int k = 0; k < FB / 256; ++k) {
      a += sCnt[PIDX(base + k)]; sCnt[PIDX(base + k)] = a;
      b += sPos[PIDX(base + k)]; sPos[PIDX(base + k)] = b;
    }
  }
  float ta = a, tb = b;
  blockScan2(a, b, tA, tB, tid);                  // inclusive over thread totals
  {
    float offC = a - ta, offS = b - tb;           // exclusive prefix for this thread
    int base = tid * (FB / 256);
    for (int k = 0; k < FB / 256; ++k) { sCnt[PIDX(base + k)] += offC; sPos[PIDX(base + k)] += offS; }
  }
  __syncthreads();
  // target cdf: parallel scan of th row (jnp: cumsum then /total*N in f32)
  {
    float h = th[(size_t)c * NBINS + tid], dummy = 0.f;
    blockScan2(h, dummy, tA, tB, tid);
    sCdf[tid] = h;
  }
  __syncthreads();
  float total = sCdf[NBINS - 1];
  int j = tid;
  float cs = (sCdf[j] / total) * (float)N_EL;
  int kj = (int)floorf(cs);
  kj = min(max(kj, 0), N_EL);
  float fk = (float)kj;
  float totCnt = sCnt[PIDX(FB - 1)];
  float totSumX = mn * totCnt + w * sPos[PIDX(FB - 1)];
  float S1;                                       // sum of the kj smallest x
  if (kj <= 0) S1 = 0.f;
  else if (fk >= totCnt) S1 = totSumX;
  else {
    int lo = 0, hi = FB - 1;
    while (lo < hi) { int mid = (lo + hi) >> 1; if (sCnt[PIDX(mid)] >= fk) hi = mid; else lo = mid + 1; }
    float cP = lo ? sCnt[PIDX(lo - 1)] : 0.f, pP = lo ? sPos[PIDX(lo - 1)] : 0.f;
    float cb = sCnt[PIDX(lo)] - cP, pb = sPos[PIDX(lo)] - pP;
    float Ppart = pP + (fk - cP) * (cb > 0.f ? pb / cb : 0.f);
    S1 = mn * fk + w * Ppart;
  }
  sS1[j] = S1; sK[j] = kj;
  // coarse 256-bin hist from fine prefix sums (4080 = 16*255)
  float hj = sCnt[PIDX(16 * j + 15)] - (j ? sCnt[PIDX(16 * j - 1)] : 0.f);
  dout[1 + (size_t)c * NBINS + j] = hj;
  __syncthreads();
  int kP = j ? sK[j - 1] : 0;
  float S1P = j ? sS1[j - 1] : 0.f;
  // last bin absorbs everything up to N exactly (clip in searchsorted)
  float kjEff = (j == NBINS - 1) ? (float)N_EL : (float)kj;
  float S1Eff = (j == NBINS - 1) ? totSumX : S1;
  float cj = kjEff - (float)kP;
  float dS1 = S1Eff - S1P;
  float tmn = tmn_p[c], tmx = tmx_p[c];
  float tj = ((float)j / 255.0f) * (tmx - tmn) + tmn;
  float part = cj * tj * tj - 2.0f * tj * dS1;
  for (int o = 32; o > 0; o >>= 1) part += __shfl_xor(part, o);
  if ((tid & 63) == 0) red[tid >> 6] = part;
  __syncthreads();
  if (tid == 0) {
    float sx2 = 0.f;
    for (int k = 0; k < BPC_MM; ++k) sx2 += sx2p[c * BPC_MM + k];
    float Lc = red[0] + red[1] + red[2] + red[3] + sx2;
    atomicAdd(&dout[0], Lc * (0.01f / ((float)C_CH * (float)N_EL)));
    dout[1 + C_CH * NBINS + c] = mn;              // cur_min
    dout[1 + C_CH * NBINS + C_CH + c] = mx;       // cur_max
  }
}

extern "C" void kernel_launch(void* const* d_in, const int* in_sizes, int n_in,
                              void* d_out, int out_size, void* d_ws, size_t ws_size,
                              hipStream_t stream) {
  const float* inp  = (const float*)d_in[0];
  const float* mask = (const float*)d_in[1];
  const float* th   = (const float*)d_in[2];
  const float* tmn  = (const float*)d_in[3];
  const float* tmx  = (const float*)d_in[4];
  float* out = (float*)d_out;

  u64* fineP   = (u64*)d_ws;                                  // 8B-aligned first
  float* pmn   = (float*)(fineP + (size_t)C_CH * BPC_H * FB);
  float* pmx   = pmn + C_CH * BPC_MM;
  float* sx2p  = pmx + C_CH * BPC_MM;

  hipLaunchKernelGGL(k_minmax, dim3(C_CH * BPC_MM), dim3(256), 0, stream,
                     inp, mask, pmn, pmx, sx2p);
  hipLaunchKernelGGL(k_hist, dim3(C_CH * BPC_H), dim3(1024), 0, stream,
                     inp, mask, pmn, pmx, fineP, out);
  hipLaunchKernelGGL(k_fin, dim3(C_CH), dim3(256), 0, stream,
                     th, tmn, tmx, pmn, pmx, sx2p, fineP, out);
}

// Round 5
// 228.217 us; speedup vs baseline: 1.0161x; 1.0161x over previous
//
#include <hip/hip_runtime.h>

#define C_CH 128
#define N_EL 262144          // 512*512 per channel
#define NBINS 256
#define FB 4096              // fine bins used: 0..4080 (4080 = 16*255)
#define FBINS 4080.0f
#define BPC_MM 16            // blocks per channel, minmax pass
#define BPC_H 4              // blocks per channel, hist pass
typedef unsigned long long u64;

// padded LDS index: +1 float per 32 to break 32-way bank conflicts on tid*16 slices
#define PIDX(i) ((i) + ((i) >> 5))
#define FBP (FB + (FB >> 5))

// ---------------- pass A: per-block min/max/sumx2 partials (plain stores, no init needed)
__global__ __launch_bounds__(256) void k_minmax(const float* __restrict__ inp,
                                                const float* __restrict__ mask,
                                                float* __restrict__ pmn,
                                                float* __restrict__ pmx,
                                                float* __restrict__ sx2p) {
  const int SEG = N_EL / BPC_MM;      // 16384 elements, 4096 float4
  int c = blockIdx.x / BPC_MM;
  int seg = blockIdx.x % BPC_MM;
  const float4* in4 = (const float4*)(inp + (size_t)c * N_EL + (size_t)seg * SEG);
  const float4* mk4 = (const float4*)(mask + (size_t)seg * SEG);
  float mn = INFINITY, mx = -INFINITY, sx2 = 0.f;
  int tid = threadIdx.x;
#pragma unroll
  for (int i = 0; i < 4; ++i) {
    float4 av[4], mv[4];
#pragma unroll
    for (int k = 0; k < 4; ++k) av[k] = in4[i * 1024 + k * 256 + tid];
#pragma unroll
    for (int k = 0; k < 4; ++k) mv[k] = mk4[i * 1024 + k * 256 + tid];
#pragma unroll
    for (int k = 0; k < 4; ++k) {
      float x0 = av[k].x * mv[k].x, x1 = av[k].y * mv[k].y;
      float x2 = av[k].z * mv[k].z, x3 = av[k].w * mv[k].w;
      mn = fminf(mn, fminf(fminf(x0, x1), fminf(x2, x3)));
      mx = fmaxf(mx, fmaxf(fmaxf(x0, x1), fmaxf(x2, x3)));
      sx2 += x0 * x0 + x1 * x1 + x2 * x2 + x3 * x3;
    }
  }
  for (int o = 32; o > 0; o >>= 1) {
    mn = fminf(mn, __shfl_xor(mn, o));
    mx = fmaxf(mx, __shfl_xor(mx, o));
    sx2 += __shfl_xor(sx2, o);
  }
  __shared__ float smn[4], smx[4], ssx[4];
  if ((tid & 63) == 0) { smn[tid >> 6] = mn; smx[tid >> 6] = mx; ssx[tid >> 6] = sx2; }
  __syncthreads();
  if (tid == 0) {
    pmn[blockIdx.x] = fminf(fminf(smn[0], smn[1]), fminf(smn[2], smn[3]));
    pmx[blockIdx.x] = fmaxf(fmaxf(smx[0], smx[1]), fmaxf(smx[2], smx[3]));
    sx2p[blockIdx.x] = ssx[0] + ssx[1] + ssx[2] + ssx[3];
  }
}

// ---------------- pass B: dual-copy LDS fine hist (packed u64), plain-store flush
__global__ __launch_bounds__(1024) void k_hist(const float* __restrict__ inp,
                                               const float* __restrict__ mask,
                                               const float* __restrict__ pmn,
                                               const float* __restrict__ pmx,
                                               u64* __restrict__ fineP,
                                               float* __restrict__ dout) {
  __shared__ u64 lh[2][FB];           // exactly 64 KB: two copies, wave-interleaved
  const int SEG = N_EL / BPC_H;       // 65536 elements, 16384 float4
  int c = blockIdx.x / BPC_H, seg = blockIdx.x % BPC_H;
  int tid = threadIdx.x;
  u64* myh = lh[(tid >> 6) & 1];      // alternate waves -> alternate copies
  for (int i = tid; i < 2 * FB; i += 1024) ((u64*)lh)[i] = 0ull;
  if (blockIdx.x == 0 && tid == 0) dout[0] = 0.f;   // loss accumulator for k_fin
  __syncthreads();
  // block-uniform min/max from partials (scalar loads, L2-hot)
  float mn = INFINITY, mx = -INFINITY;
#pragma unroll
  for (int k = 0; k < BPC_MM; ++k) {
    mn = fminf(mn, pmn[c * BPC_MM + k]);
    mx = fmaxf(mx, pmx[c * BPC_MM + k]);
  }
  float inv = FBINS / fmaxf(mx - mn, 1e-8f);
  const float4* in4 = (const float4*)(inp + (size_t)c * N_EL + (size_t)seg * SEG);
  const float4* mk4 = (const float4*)(mask + (size_t)seg * SEG);
#pragma unroll
  for (int i = 0; i < 4; ++i) {
    float4 av[4], mv[4];
#pragma unroll
    for (int k = 0; k < 4; ++k) av[k] = in4[i * 4096 + k * 1024 + tid];
#pragma unroll
    for (int k = 0; k < 4; ++k) mv[k] = mk4[i * 4096 + k * 1024 + tid];
#pragma unroll
    for (int k = 0; k < 4; ++k) {
      float xs[4] = {av[k].x * mv[k].x, av[k].y * mv[k].y, av[k].z * mv[k].z, av[k].w * mv[k].w};
#pragma unroll
      for (int e = 0; e < 4; ++e) {
        float vv = (xs[e] - mn) * inv;             // position in fine-bin units
        vv = fminf(fmaxf(vv, 0.f), FBINS);         // [0, 4080]
        int fb = (int)vv;
        float frac = vv - (float)fb;               // [0,1)
        u64 pkt = (1ull << 46) | (u64)(frac * 268435456.0f);  // frac * 2^28
        atomicAdd(&myh[fb], pkt);
      }
    }
  }
  __syncthreads();   // order all LDS atomics before flush
  // flush merged fine hist: plain u64 stores, disjoint per-block slice
  // (each copy's frac field < 2^45, so the sum stays below the cnt field at bit 46)
  for (int i = tid; i < FB; i += 1024)
    fineP[(size_t)blockIdx.x * FB + i] = lh[0][i] + lh[1][i];
}

// inclusive block scan of (a,b) over 256 threads: wave shfl scan + wave-total combine
__device__ __forceinline__ void blockScan2(float& a, float& b, float* tA, float* tB, int tid) {
  int lane = tid & 63, wave = tid >> 6;
#pragma unroll
  for (int o = 1; o < 64; o <<= 1) {
    float na = __shfl_up(a, o), nb = __shfl_up(b, o);
    if (lane >= o) { a += na; b += nb; }
  }
  if (lane == 63) { tA[wave] = a; tB[wave] = b; }
  __syncthreads();
  float offA = 0.f, offB = 0.f;
  for (int wv = 0; wv < 3; ++wv)
    if (wv < wave) { offA += tA[wv]; offB += tB[wv]; }
  a += offA; b += offB;
  __syncthreads();
}

// ---------------- pass C: scans + searchsorted-equivalent + loss
__global__ __launch_bounds__(256) void k_fin(const float* __restrict__ th,
                                             const float* __restrict__ tmn_p,
                                             const float* __restrict__ tmx_p,
                                             const float* __restrict__ pmn,
                                             const float* __restrict__ pmx,
                                             const float* __restrict__ sx2p,
                                             const u64* __restrict__ fineP,
                                             float* __restrict__ dout) {
  __shared__ float sCnt[FBP], sPos[FBP];
  __shared__ float tA[4], tB[4];
  __shared__ float sCdf[NBINS];
  __shared__ float sS1[NBINS];
  __shared__ int sK[NBINS];
  __shared__ float red[4];
  __shared__ float sMnMx[2];
  int c = blockIdx.x, tid = threadIdx.x;
  if (tid == 0) {
    float m = INFINITY;
    for (int k = 0; k < BPC_MM; ++k) m = fminf(m, pmn[c * BPC_MM + k]);
    sMnMx[0] = m;
  }
  if (tid == 64) {
    float M = -INFINITY;
    for (int k = 0; k < BPC_MM; ++k) M = fmaxf(M, pmx[c * BPC_MM + k]);
    sMnMx[1] = M;
  }
  const u64 FMASK = (1ull << 46) - 1;
  for (int i = tid; i < FB; i += 256) {
    u64 csum = 0ull, fsum = 0ull;
#pragma unroll
    for (int p = 0; p < BPC_H; ++p) {
      u64 pk = fineP[(size_t)(c * BPC_H + p) * FB + i];
      csum += pk >> 46;
      fsum += pk & FMASK;
    }
    float cn = (float)(unsigned)csum;
    sCnt[PIDX(i)] = cn;
    sPos[PIDX(i)] = cn * (float)i + (float)fsum * (1.0f / 268435456.0f);
  }
  __syncthreads();
  float mn = sMnMx[0], mx = sMnMx[1];
  float w = fmaxf(mx - mn, 1e-8f) / FBINS;        // fine-bin width
  // inclusive scan: 16-elem serial per thread, then parallel scan of thread totals
  float a = 0.f, b = 0.f;
  {
    int base = tid * (FB / 256);
    for (int k = 0; k < FB / 256; ++k) {
      a += sCnt[PIDX(base + k)]; sCnt[PIDX(base + k)] = a;
      b += sPos[PIDX(base + k)]; sPos[PIDX(base + k)] = b;
    }
  }
  float ta = a, tb = b;
  blockScan2(a, b, tA, tB, tid);                  // inclusive over thread totals
  {
    float offC = a - ta, offS = b - tb;           // exclusive prefix for this thread
    int base = tid * (FB / 256);
    for (int k = 0; k < FB / 256; ++k) { sCnt[PIDX(base + k)] += offC; sPos[PIDX(base + k)] += offS; }
  }
  __syncthreads();
  // target cdf: parallel scan of th row (jnp: cumsum then /total*N in f32)
  {
    float h = th[(size_t)c * NBINS + tid], dummy = 0.f;
    blockScan2(h, dummy, tA, tB, tid);
    sCdf[tid] = h;
  }
  __syncthreads();
  float total = sCdf[NBINS - 1];
  int j = tid;
  float cs = (sCdf[j] / total) * (float)N_EL;
  int kj = (int)floorf(cs);
  kj = min(max(kj, 0), N_EL);
  float fk = (float)kj;
  float totCnt = sCnt[PIDX(FB - 1)];
  float totSumX = mn * totCnt + w * sPos[PIDX(FB - 1)];
  float S1;                                       // sum of the kj smallest x
  if (kj <= 0) S1 = 0.f;
  else if (fk >= totCnt) S1 = totSumX;
  else {
    int lo = 0, hi = FB - 1;
    while (lo < hi) { int mid = (lo + hi) >> 1; if (sCnt[PIDX(mid)] >= fk) hi = mid; else lo = mid + 1; }
    float cP = lo ? sCnt[PIDX(lo - 1)] : 0.f, pP = lo ? sPos[PIDX(lo - 1)] : 0.f;
    float cb = sCnt[PIDX(lo)] - cP, pb = sPos[PIDX(lo)] - pP;
    float Ppart = pP + (fk - cP) * (cb > 0.f ? pb / cb : 0.f);
    S1 = mn * fk + w * Ppart;
  }
  sS1[j] = S1; sK[j] = kj;
  // coarse 256-bin hist from fine prefix sums (4080 = 16*255)
  float hj = sCnt[PIDX(16 * j + 15)] - (j ? sCnt[PIDX(16 * j - 1)] : 0.f);
  dout[1 + (size_t)c * NBINS + j] = hj;
  __syncthreads();
  int kP = j ? sK[j - 1] : 0;
  float S1P = j ? sS1[j - 1] : 0.f;
  // last bin absorbs everything up to N exactly (clip in searchsorted)
  float kjEff = (j == NBINS - 1) ? (float)N_EL : (float)kj;
  float S1Eff = (j == NBINS - 1) ? totSumX : S1;
  float cj = kjEff - (float)kP;
  float dS1 = S1Eff - S1P;
  float tmn = tmn_p[c], tmx = tmx_p[c];
  float tj = ((float)j / 255.0f) * (tmx - tmn) + tmn;
  float part = cj * tj * tj - 2.0f * tj * dS1;
  for (int o = 32; o > 0; o >>= 1) part += __shfl_xor(part, o);
  if ((tid & 63) == 0) red[tid >> 6] = part;
  __syncthreads();
  if (tid == 0) {
    float sx2 = 0.f;
    for (int k = 0; k < BPC_MM; ++k) sx2 += sx2p[c * BPC_MM + k];
    float Lc = red[0] + red[1] + red[2] + red[3] + sx2;
    atomicAdd(&dout[0], Lc * (0.01f / ((float)C_CH * (float)N_EL)));
    dout[1 + C_CH * NBINS + c] = mn;              // cur_min
    dout[1 + C_CH * NBINS + C_CH + c] = mx;       // cur_max
  }
}

extern "C" void kernel_launch(void* const* d_in, const int* in_sizes, int n_in,
                              void* d_out, int out_size, void* d_ws, size_t ws_size,
                              hipStream_t stream) {
  const float* inp  = (const float*)d_in[0];
  const float* mask = (const float*)d_in[1];
  const float* th   = (const float*)d_in[2];
  const float* tmn  = (const float*)d_in[3];
  const float* tmx  = (const float*)d_in[4];
  float* out = (float*)d_out;

  u64* fineP   = (u64*)d_ws;                                  // 8B-aligned first
  float* pmn   = (float*)(fineP + (size_t)C_CH * BPC_H * FB);
  float* pmx   = pmn + C_CH * BPC_MM;
  float* sx2p  = pmx + C_CH * BPC_MM;

  hipLaunchKernelGGL(k_minmax, dim3(C_CH * BPC_MM), dim3(256), 0, stream,
                     inp, mask, pmn, pmx, sx2p);
  hipLaunchKernelGGL(k_hist, dim3(C_CH * BPC_H), dim3(1024), 0, stream,
                     inp, mask, pmn, pmx, fineP, out);
  hipLaunchKernelGGL(k_fin, dim3(C_CH), dim3(256), 0, stream,
                     th, tmn, tmx, pmn, pmx, sx2p, fineP, out);
}